// Round 1
// baseline (441.675 us; speedup 1.0000x reference)
//
#include <hip/hip_runtime.h>

#define B_ 16
#define N_ 1024
#define K_ 16
#define F_ 128
#define L_ 4
#define DIN_ 257

__device__ __forceinline__ float silu_f(float x) {
    return x / (1.0f + __expf(-x));
}

// ---------------- h0 = emb[z] ----------------
__global__ __launch_bounds__(256) void k_embed(const int* __restrict__ z,
                                               const float* __restrict__ emb,
                                               float* __restrict__ h) {
    int t = blockIdx.x * 256 + threadIdx.x;  // one thread per (node, float4)
    int node = t >> 5;
    int f4 = (t & 31) << 2;
    if (node >= B_ * N_) return;
    int zi = z[node];
    float4 v = *reinterpret_cast<const float4*>(&emb[zi * F_ + f4]);
    *reinterpret_cast<float4*>(&h[node * F_ + f4]) = v;
}

// ---------------- periodic KNN: wave per row i ----------------
// Per pair: only the 2 nearest integer shifts per component can win
// (cell ~ 8I; third image is dominated by >= ~36 in d2). Evaluate the 8
// combos in ascending original-shift-index order with strict < (matches
// reference tie-break). Arithmetic form matches reference: (rel+s)@cell.
__global__ __launch_bounds__(256) void k_knn(const float* __restrict__ x,
                                             const float* __restrict__ cell,
                                             int* __restrict__ idx_o,
                                             float* __restrict__ vec_o,
                                             float* __restrict__ d_o) {
    __shared__ float fr[N_ * 3];
    int b = blockIdx.x >> 8;            // 256 blocks per batch
    int ib = (blockIdx.x & 255) << 2;   // 4 rows per block (1 per wave)
    const float* xb = x + b * N_ * 3;
    for (int u = threadIdx.x; u < N_ * 3; u += 256) {
        float xv = xb[u];
        fr[u] = xv - floorf(xv);
    }
    __syncthreads();
    int wave = threadIdx.x >> 6;
    int lane = threadIdx.x & 63;
    int i = ib + wave;

    const float* cb = cell + b * 9;
    float c00 = cb[0], c01 = cb[1], c02 = cb[2];
    float c10 = cb[3], c11 = cb[4], c12 = cb[5];
    float c20 = cb[6], c21 = cb[7], c22 = cb[8];
    float fi0 = fr[i * 3 + 0], fi1 = fr[i * 3 + 1], fi2 = fr[i * 3 + 2];

    float d2a[16];
    int pka[16];
#pragma unroll
    for (int t = 0; t < 16; ++t) {
        int j = t * 64 + lane;
        float r0 = fr[j * 3 + 0] - fi0;
        float r1 = fr[j * 3 + 1] - fi1;
        float r2 = fr[j * 3 + 2] - fi2;
        int s0i = (r0 > 0.f) ? -1 : 0;
        int s1i = (r1 > 0.f) ? -1 : 0;
        int s2i = (r2 > 0.f) ? -1 : 0;
        float best = 3e38f;
        int bsid = 0;
#pragma unroll
        for (int i0 = 0; i0 < 2; ++i0) {
            float rs0 = r0 + (float)(s0i + i0);
#pragma unroll
            for (int i1 = 0; i1 < 2; ++i1) {
                float rs1 = r1 + (float)(s1i + i1);
#pragma unroll
                for (int i2 = 0; i2 < 2; ++i2) {
                    float rs2 = r2 + (float)(s2i + i2);
                    float cx = fmaf(rs2, c20, fmaf(rs1, c10, rs0 * c00));
                    float cy = fmaf(rs2, c21, fmaf(rs1, c11, rs0 * c01));
                    float cz = fmaf(rs2, c22, fmaf(rs1, c12, rs0 * c02));
                    float d2 = fmaf(cz, cz, fmaf(cy, cy, cx * cx));
                    int sid = (s0i + i0 + 1) * 9 + (s1i + i1 + 1) * 3 + (s2i + i2 + 1);
                    if (d2 < best) { best = d2; bsid = sid; }
                }
            }
        }
        if (j == i) best = 3e38f;  // exclude self
        d2a[t] = best;
        pka[t] = (j << 5) | bsid;  // tie-break by smaller j (matches top_k)
    }

    // wave-level top-16 of 1024: 16 rounds of global argmin + consume.
    int sel = 0;
    for (int r = 0; r < 16; ++r) {
        float bd = 3e38f;
        int bpk = 0x7fffffff;
#pragma unroll
        for (int t = 0; t < 16; ++t) {
            bool lt = (d2a[t] < bd) || (d2a[t] == bd && pka[t] < bpk);
            if (lt) { bd = d2a[t]; bpk = pka[t]; }
        }
#pragma unroll
        for (int off = 32; off >= 1; off >>= 1) {
            float od = __shfl_xor(bd, off);
            int opk = __shfl_xor(bpk, off);
            bool lt = (od < bd) || (od == bd && opk < bpk);
            if (lt) { bd = od; bpk = opk; }
        }
        // consume winner (pk is globally unique) — static indices only
#pragma unroll
        for (int t = 0; t < 16; ++t)
            if (pka[t] == bpk) d2a[t] = 3e38f;
        if (lane == r) sel = bpk;
    }

    if (lane < 16) {
        int j = sel >> 5, sid = sel & 31;
        int s0 = sid / 9 - 1, s1 = (sid / 3) % 3 - 1, s2 = sid % 3 - 1;
        float rs0 = (fr[j * 3 + 0] - fi0) + (float)s0;
        float rs1 = (fr[j * 3 + 1] - fi1) + (float)s1;
        float rs2 = (fr[j * 3 + 2] - fi2) + (float)s2;
        float vx = fmaf(rs2, c20, fmaf(rs1, c10, rs0 * c00));
        float vy = fmaf(rs2, c21, fmaf(rs1, c11, rs0 * c01));
        float vz = fmaf(rs2, c22, fmaf(rs1, c12, rs0 * c02));
        float d2 = fmaf(vz, vz, fmaf(vy, vy, vx * vx));
        float dd = sqrtf(fmaxf(d2, 1e-12f));
        int node = b * N_ + i;
        int eo = node * K_ + lane;
        idx_o[eo] = j;
        d_o[eo] = dd;
        vec_o[eo * 3 + 0] = vx;
        vec_o[eo * 3 + 1] = vy;
        vec_o[eo * 3 + 2] = vz;
    }
}

// ---------------- fp32 GEMM: C[M x (ldc)] tile = A[M x 128] @ B[128 x 128] ----------------
// M = 16384 fixed, K = 128 fixed. blockIdx.y selects B0/B1 (n-tile of 256-wide output).
template <int TM>
__global__ __launch_bounds__(256) void k_gemm(const float* __restrict__ A,
                                              const float* __restrict__ B0,
                                              const float* __restrict__ B1,
                                              const float* __restrict__ bias,
                                              const float* __restrict__ resid,
                                              float* __restrict__ C, int ldc) {
    constexpr int MR = TM / 16;
    __shared__ float As[32][TM + 4];
    __shared__ float Bs[32][132];
    const float* Bp = (blockIdx.y == 0) ? B0 : B1;
    int m0 = blockIdx.x * TM;
    int col0 = blockIdx.y * 128;
    int tx = threadIdx.x & 15, ty = threadIdx.x >> 4;
    float acc[MR][8];
#pragma unroll
    for (int u = 0; u < MR; ++u)
#pragma unroll
        for (int v = 0; v < 8; ++v) acc[u][v] = 0.f;

    for (int kc = 0; kc < 128; kc += 32) {
#pragma unroll
        for (int p = 0; p < TM / 32; ++p) {
            int id = threadIdx.x + p * 256;
            int m = id >> 3;
            int k4 = (id & 7) << 2;
            float4 av = *reinterpret_cast<const float4*>(&A[(size_t)(m0 + m) * 128 + kc + k4]);
            As[k4 + 0][m] = av.x;
            As[k4 + 1][m] = av.y;
            As[k4 + 2][m] = av.z;
            As[k4 + 3][m] = av.w;
        }
#pragma unroll
        for (int p = 0; p < 4; ++p) {
            int id = threadIdx.x + p * 256;
            int kk = id >> 5;
            int n4 = (id & 31) << 2;
            float4 bv = *reinterpret_cast<const float4*>(&Bp[(size_t)(kc + kk) * 128 + n4]);
            *reinterpret_cast<float4*>(&Bs[kk][n4]) = bv;
        }
        __syncthreads();
#pragma unroll
        for (int kk = 0; kk < 32; ++kk) {
            float a[MR], bb[8];
#pragma unroll
            for (int u = 0; u < MR; u += 4) {
                float4 t4 = *reinterpret_cast<const float4*>(&As[kk][ty * MR + u]);
                a[u] = t4.x; a[u + 1] = t4.y; a[u + 2] = t4.z; a[u + 3] = t4.w;
            }
#pragma unroll
            for (int v = 0; v < 8; v += 4) {
                float4 t4 = *reinterpret_cast<const float4*>(&Bs[kk][tx * 8 + v]);
                bb[v] = t4.x; bb[v + 1] = t4.y; bb[v + 2] = t4.z; bb[v + 3] = t4.w;
            }
#pragma unroll
            for (int u = 0; u < MR; ++u)
#pragma unroll
                for (int v = 0; v < 8; ++v) acc[u][v] = fmaf(a[u], bb[v], acc[u][v]);
        }
        __syncthreads();
    }
#pragma unroll
    for (int u = 0; u < MR; ++u) {
        int m = m0 + ty * MR + u;
        float o[8];
#pragma unroll
        for (int v = 0; v < 8; ++v) {
            int n = tx * 8 + v;
            float val = acc[u][v];
            if (bias) val += bias[n];
            if (resid) val += resid[(size_t)m * 128 + n];
            o[v] = val;
        }
        float4 o0 = {o[0], o[1], o[2], o[3]};
        float4 o1 = {o[4], o[5], o[6], o[7]};
        *reinterpret_cast<float4*>(&C[(size_t)m * ldc + col0 + tx * 8]) = o0;
        *reinterpret_cast<float4*>(&C[(size_t)m * ldc + col0 + tx * 8 + 4]) = o1;
    }
}

// ---------------- per-edge silu + mean (savg) ----------------
// thread (g = node-in-block, fc = 8-feature chunk)
__global__ __launch_bounds__(256) void k_edge(const float* __restrict__ UV,
                                              const int* __restrict__ idx,
                                              const float* __restrict__ nd,
                                              const float* __restrict__ w1d,
                                              const float* __restrict__ b1,
                                              float* __restrict__ savg) {
    int g = threadIdx.x >> 4;
    int fc = threadIdx.x & 15;
    int node = blockIdx.x * 16 + g;
    int b = node >> 10;
    int f0 = fc * 8;
    float u[8], wd[8], bb[8], acc[8];
#pragma unroll
    for (int q = 0; q < 8; q += 4) {
        float4 t = *reinterpret_cast<const float4*>(&UV[(size_t)node * 256 + f0 + q]);
        u[q] = t.x; u[q + 1] = t.y; u[q + 2] = t.z; u[q + 3] = t.w;
        float4 t2 = *reinterpret_cast<const float4*>(&w1d[f0 + q]);
        wd[q] = t2.x; wd[q + 1] = t2.y; wd[q + 2] = t2.z; wd[q + 3] = t2.w;
        float4 t3 = *reinterpret_cast<const float4*>(&b1[f0 + q]);
        bb[q] = t3.x; bb[q + 1] = t3.y; bb[q + 2] = t3.z; bb[q + 3] = t3.w;
    }
#pragma unroll
    for (int q = 0; q < 8; ++q) acc[q] = 0.f;
    int ebase = node * K_;
    for (int e = 0; e < K_; ++e) {
        int j = idx[ebase + e];
        float dd = nd[ebase + e];
        const float* vp = &UV[(size_t)(b * N_ + j) * 256 + 128 + f0];
#pragma unroll
        for (int q = 0; q < 8; q += 4) {
            float4 t = *reinterpret_cast<const float4*>(&vp[q]);
            float v4[4] = {t.x, t.y, t.z, t.w};
#pragma unroll
            for (int w = 0; w < 4; ++w) {
                float pre = u[q + w] + v4[w] + fmaf(dd, wd[q + w], bb[q + w]);
                acc[q + w] += silu_f(pre);
            }
        }
    }
    const float inv_k = 1.0f / (float)K_;
#pragma unroll
    for (int q = 0; q < 8; q += 4) {
        float4 o = {acc[q] * inv_k, acc[q + 1] * inv_k, acc[q + 2] * inv_k, acc[q + 3] * inv_k};
        *reinterpret_cast<float4*>(&savg[(size_t)node * 128 + f0 + q]) = o;
    }
}

// ---------------- final head: per-edge weight, delta, output ----------------
__global__ __launch_bounds__(256) void k_final(const float* __restrict__ P,
                                               const int* __restrict__ idx,
                                               const float* __restrict__ nd,
                                               const float* __restrict__ nvec,
                                               const float* __restrict__ A1d,
                                               const float* __restrict__ a1v,
                                               const float* __restrict__ A2v,
                                               const float* __restrict__ a2v,
                                               const float* __restrict__ x,
                                               const float* __restrict__ cell,
                                               float* __restrict__ out) {
    __shared__ float plds[16][256];  // [e][g*16+fc]
    __shared__ float wlds[16][17];
    __shared__ float dclds[16][3];
    int g = threadIdx.x >> 4, fc = threadIdx.x & 15;
    int node = blockIdx.x * 16 + g;
    int b = node >> 10;
    int f0 = fc * 8;
    float pa[8], ad[8], aa[8], a2r[8];
#pragma unroll
    for (int q = 0; q < 8; q += 4) {
        float4 t = *reinterpret_cast<const float4*>(&P[(size_t)node * 256 + f0 + q]);
        pa[q] = t.x; pa[q + 1] = t.y; pa[q + 2] = t.z; pa[q + 3] = t.w;
        float4 t2 = *reinterpret_cast<const float4*>(&A1d[f0 + q]);
        ad[q] = t2.x; ad[q + 1] = t2.y; ad[q + 2] = t2.z; ad[q + 3] = t2.w;
        float4 t3 = *reinterpret_cast<const float4*>(&a1v[f0 + q]);
        aa[q] = t3.x; aa[q + 1] = t3.y; aa[q + 2] = t3.z; aa[q + 3] = t3.w;
        float4 t4 = *reinterpret_cast<const float4*>(&A2v[f0 + q]);
        a2r[q] = t4.x; a2r[q + 1] = t4.y; a2r[q + 2] = t4.z; a2r[q + 3] = t4.w;
    }
    int ebase = node * K_;
    for (int e = 0; e < K_; ++e) {
        int j = idx[ebase + e];
        float dd = nd[ebase + e];
        const float* vp = &P[(size_t)(b * N_ + j) * 256 + 128 + f0];
        float part = 0.f;
#pragma unroll
        for (int q = 0; q < 8; q += 4) {
            float4 t = *reinterpret_cast<const float4*>(&vp[q]);
            float v4[4] = {t.x, t.y, t.z, t.w};
#pragma unroll
            for (int w = 0; w < 4; ++w) {
                float pre = pa[q + w] + v4[w] + fmaf(dd, ad[q + w], aa[q + w]);
                part = fmaf(silu_f(pre), a2r[q + w], part);
            }
        }
        plds[e][(g << 4) | fc] = part;
    }
    __syncthreads();
    {
        int g2 = threadIdx.x >> 4, e2 = threadIdx.x & 15;
        float w = a2v[0];
#pragma unroll
        for (int f2 = 0; f2 < 16; ++f2) w += plds[e2][(g2 << 4) | f2];
        wlds[g2][e2] = w;
    }
    __syncthreads();
    if (threadIdx.x < 48) {
        int gg = threadIdx.x & 15, c = threadIdx.x >> 4;
        int noded = blockIdx.x * 16 + gg;
        float dc = 0.f;
#pragma unroll
        for (int e = 0; e < K_; ++e)
            dc = fmaf(wlds[gg][e], nvec[(size_t)(noded * K_ + e) * 3 + c], dc);
        dclds[gg][c] = dc;
    }
    __syncthreads();
    if (threadIdx.x < 48) {
        int gg = threadIdx.x & 15, c = threadIdx.x >> 4;
        int noded = blockIdx.x * 16 + gg;
        int bb2 = noded >> 10;
        const float* cb = cell + bb2 * 9;
        float c00 = cb[0], c01 = cb[1], c02 = cb[2];
        float c10 = cb[3], c11 = cb[4], c12 = cb[5];
        float c20 = cb[6], c21 = cb[7], c22 = cb[8];
        float det = c00 * (c11 * c22 - c12 * c21) - c01 * (c10 * c22 - c12 * c20) +
                    c02 * (c10 * c21 - c11 * c20);
        float rdet = 1.0f / det;
        float i0c, i1c, i2c;  // column c of inv(cell)
        if (c == 0) {
            i0c = (c11 * c22 - c12 * c21) * rdet;
            i1c = -(c10 * c22 - c12 * c20) * rdet;
            i2c = (c10 * c21 - c11 * c20) * rdet;
        } else if (c == 1) {
            i0c = -(c01 * c22 - c02 * c21) * rdet;
            i1c = (c00 * c22 - c02 * c20) * rdet;
            i2c = -(c00 * c21 - c01 * c20) * rdet;
        } else {
            i0c = (c01 * c12 - c02 * c11) * rdet;
            i1c = -(c00 * c12 - c02 * c10) * rdet;
            i2c = (c00 * c11 - c01 * c10) * rdet;
        }
        float df = dclds[gg][0] * i0c + dclds[gg][1] * i1c + dclds[gg][2] * i2c;
        out[(size_t)noded * 3 + c] = x[(size_t)noded * 3 + c] + df;
    }
}

extern "C" void kernel_launch(void* const* d_in, const int* in_sizes, int n_in,
                              void* d_out, int out_size, void* d_ws, size_t ws_size,
                              hipStream_t stream) {
    (void)in_sizes; (void)n_in; (void)out_size; (void)ws_size;
    const float* cell = (const float*)d_in[0];
    const float* x    = (const float*)d_in[1];
    const int*   z    = (const int*)d_in[2];
    const float* emb  = (const float*)d_in[4];
    const float* W1   = (const float*)d_in[5];
    const float* b1   = (const float*)d_in[6];
    const float* W2   = (const float*)d_in[7];
    const float* b2   = (const float*)d_in[8];
    const float* A1   = (const float*)d_in[9];
    const float* a1   = (const float*)d_in[10];
    const float* A2   = (const float*)d_in[11];
    const float* a2   = (const float*)d_in[12];
    float* out = (float*)d_out;

    char* ws = (char*)d_ws;
    size_t off = 0;
    auto alloc = [&](size_t bytes) {
        void* p = ws + off;
        off = (off + bytes + 255) & ~(size_t)255;
        return p;
    };
    int* idx    = (int*)alloc((size_t)B_ * N_ * K_ * 4);
    float* nd   = (float*)alloc((size_t)B_ * N_ * K_ * 4);
    float* nvec = (float*)alloc((size_t)B_ * N_ * K_ * 3 * 4);
    float* h0   = (float*)alloc((size_t)B_ * N_ * F_ * 4);
    float* h1   = (float*)alloc((size_t)B_ * N_ * F_ * 4);
    float* uv   = (float*)alloc((size_t)B_ * N_ * 256 * 4);
    float* sv   = (float*)alloc((size_t)B_ * N_ * F_ * 4);

    k_embed<<<2048, 256, 0, stream>>>(z, emb, h0);
    k_knn<<<4096, 256, 0, stream>>>(x, cell, idx, nvec, nd);

    float* hc = h0;
    float* hn = h1;
    for (int l = 0; l < L_; ++l) {
        const float* W1l = W1 + (size_t)l * DIN_ * F_;
        k_gemm<128><<<dim3(128, 2), 256, 0, stream>>>(hc, W1l, W1l + 128 * F_, nullptr,
                                                      nullptr, uv, 256);
        k_edge<<<1024, 256, 0, stream>>>(uv, idx, nd, W1l + 256 * F_, b1 + l * F_, sv);
        k_gemm<64><<<dim3(256, 1), 256, 0, stream>>>(sv, W2 + (size_t)l * F_ * F_, nullptr,
                                                     b2 + l * F_, hc, hn, 128);
        float* tmp = hc; hc = hn; hn = tmp;
    }
    k_gemm<128><<<dim3(128, 2), 256, 0, stream>>>(hc, A1, A1 + 128 * F_, nullptr, nullptr,
                                                  uv, 256);
    k_final<<<1024, 256, 0, stream>>>(uv, idx, nd, nvec, A1 + 256 * F_, a1, A2, a2, x, cell,
                                      out);
}

// Round 2
// 347.957 us; speedup vs baseline: 1.2693x; 1.2693x over previous
//
#include <hip/hip_runtime.h>

#define B_ 16
#define N_ 1024
#define K_ 16
#define F_ 128
#define L_ 4
#define DIN_ 257

typedef __bf16 bf16x8 __attribute__((ext_vector_type(8)));
typedef float f32x4 __attribute__((ext_vector_type(4)));

__device__ __forceinline__ float silu_f(float x) {
    return x / (1.0f + __expf(-x));
}

__device__ __forceinline__ unsigned short f2bf_bits(float f) {
    unsigned u = __builtin_bit_cast(unsigned, f);
    return (unsigned short)((u + 0x7FFFu + ((u >> 16) & 1u)) >> 16);
}

// ---------------- h0 = emb[z] ----------------
__global__ __launch_bounds__(256) void k_embed(const int* __restrict__ z,
                                               const float* __restrict__ emb,
                                               float* __restrict__ h) {
    int t = blockIdx.x * 256 + threadIdx.x;  // one thread per (node, float4)
    int node = t >> 5;
    int f4 = (t & 31) << 2;
    if (node >= B_ * N_) return;
    int zi = z[node];
    float4 v = *reinterpret_cast<const float4*>(&emb[zi * F_ + f4]);
    *reinterpret_cast<float4*>(&h[node * F_ + f4]) = v;
}

// ---------------- weight pack/convert: fp32 [k][n] -> bf16 [n][k] ----------------
__global__ __launch_bounds__(256) void k_wconv(const float* __restrict__ W1,
                                               const float* __restrict__ W2,
                                               const float* __restrict__ A1,
                                               unsigned short* __restrict__ Wt1,
                                               unsigned short* __restrict__ Wt2,
                                               unsigned short* __restrict__ At1) {
    int id = blockIdx.x * 256 + threadIdx.x;
    if (id < L_ * 256 * 128) {
        int k = id & 127, n = (id >> 7) & 255, l = id >> 15;
        float v = (n < 128) ? W1[(size_t)l * DIN_ * F_ + (size_t)k * F_ + n]
                            : W1[(size_t)l * DIN_ * F_ + (size_t)(128 + k) * F_ + (n - 128)];
        Wt1[id] = f2bf_bits(v);
        return;
    }
    id -= L_ * 256 * 128;
    if (id < L_ * 128 * 128) {
        int k = id & 127, n = (id >> 7) & 127, l = id >> 14;
        Wt2[id] = f2bf_bits(W2[(size_t)l * F_ * F_ + (size_t)k * F_ + n]);
        return;
    }
    id -= L_ * 128 * 128;
    if (id < 256 * 128) {
        int k = id & 127, n = id >> 7;
        float v = (n < 128) ? A1[(size_t)k * 128 + n]
                            : A1[(size_t)(128 + k) * 128 + (n - 128)];
        At1[id] = f2bf_bits(v);
    }
}

// ---------------- periodic KNN: wave per row i ----------------
// Per pair: only the 2 nearest integer shifts per component can win
// (cell ~ 8I). Evaluate the 8 combos in ascending original-shift-index
// order with strict < (matches reference tie-break). Candidate d2
// arithmetic is bit-identical to the validated round-1 kernel.
__global__ __launch_bounds__(256) void k_knn(const float* __restrict__ x,
                                             const float* __restrict__ cell,
                                             int* __restrict__ idx_o,
                                             float* __restrict__ vec_o,
                                             float* __restrict__ d_o) {
    __shared__ float fr[N_ * 3];
    int b = blockIdx.x >> 8;            // 256 blocks per batch
    int ib = (blockIdx.x & 255) << 2;   // 4 rows per block (1 per wave)
    const float* xb = x + b * N_ * 3;
    for (int u = threadIdx.x; u < N_ * 3; u += 256) {
        float xv = xb[u];
        fr[u] = xv - floorf(xv);
    }
    __syncthreads();
    int wave = threadIdx.x >> 6;
    int lane = threadIdx.x & 63;
    int i = ib + wave;

    const float* cb = cell + b * 9;
    float c00 = cb[0], c01 = cb[1], c02 = cb[2];
    float c10 = cb[3], c11 = cb[4], c12 = cb[5];
    float c20 = cb[6], c21 = cb[7], c22 = cb[8];
    float fi0 = fr[i * 3 + 0], fi1 = fr[i * 3 + 1], fi2 = fr[i * 3 + 2];

    float d2a[16];
    int pka[16];
#pragma unroll
    for (int t = 0; t < 16; ++t) {
        int j = t * 64 + lane;
        float r0 = fr[j * 3 + 0] - fi0;
        float r1 = fr[j * 3 + 1] - fi1;
        float r2 = fr[j * 3 + 2] - fi2;
        // s*f in {-1.f, 0.f} == (float)s*i exactly; s*f+1.f exact too.
        float s0f = (r0 > 0.f) ? -1.f : 0.f;
        float s1f = (r1 > 0.f) ? -1.f : 0.f;
        float s2f = (r2 > 0.f) ? -1.f : 0.f;
        int sid_base = ((r0 > 0.f) ? 0 : 9) + ((r1 > 0.f) ? 0 : 3) + ((r2 > 0.f) ? 0 : 1);
        float rx0 = r0 + s0f, rx1 = r0 + (s0f + 1.0f);
        float ry0 = r1 + s1f, ry1 = r1 + (s1f + 1.0f);
        float rz0 = r2 + s2f, rz1 = r2 + (s2f + 1.0f);
        float best = 3e38f;
        int bsid = 0;
#pragma unroll
        for (int cbo = 0; cbo < 8; ++cbo) {  // bit2=i0, bit1=i1, bit0=i2 (ascending sid)
            float rs0 = (cbo & 4) ? rx1 : rx0;
            float rs1 = (cbo & 2) ? ry1 : ry0;
            float rs2 = (cbo & 1) ? rz1 : rz0;
            float cx = fmaf(rs2, c20, fmaf(rs1, c10, rs0 * c00));
            float cy = fmaf(rs2, c21, fmaf(rs1, c11, rs0 * c01));
            float cz = fmaf(rs2, c22, fmaf(rs1, c12, rs0 * c02));
            float d2 = fmaf(cz, cz, fmaf(cy, cy, cx * cx));
            int sid = sid_base + ((cbo >> 2) & 1) * 9 + ((cbo >> 1) & 1) * 3 + (cbo & 1);
            if (d2 < best) { best = d2; bsid = sid; }
        }
        if (j == i) best = 3e38f;  // exclude self
        d2a[t] = best;
        pka[t] = (j << 5) | bsid;  // tie-break by smaller j (matches top_k)
    }

    // wave-level top-16 of 1024: 16 rounds of global argmin + consume.
    int sel = 0;
    for (int r = 0; r < 16; ++r) {
        float bd = 3e38f;
        int bpk = 0x7fffffff;
#pragma unroll
        for (int t = 0; t < 16; ++t) {
            bool lt = (d2a[t] < bd) || (d2a[t] == bd && pka[t] < bpk);
            if (lt) { bd = d2a[t]; bpk = pka[t]; }
        }
#pragma unroll
        for (int off = 32; off >= 1; off >>= 1) {
            float od = __shfl_xor(bd, off);
            int opk = __shfl_xor(bpk, off);
            bool lt = (od < bd) || (od == bd && opk < bpk);
            if (lt) { bd = od; bpk = opk; }
        }
#pragma unroll
        for (int t = 0; t < 16; ++t)
            if (pka[t] == bpk) d2a[t] = 3e38f;
        if (lane == r) sel = bpk;
    }

    if (lane < 16) {
        int j = sel >> 5, sid = sel & 31;
        int s0 = sid / 9 - 1, s1 = (sid / 3) % 3 - 1, s2 = sid % 3 - 1;
        float rs0 = (fr[j * 3 + 0] - fi0) + (float)s0;
        float rs1 = (fr[j * 3 + 1] - fi1) + (float)s1;
        float rs2 = (fr[j * 3 + 2] - fi2) + (float)s2;
        float vx = fmaf(rs2, c20, fmaf(rs1, c10, rs0 * c00));
        float vy = fmaf(rs2, c21, fmaf(rs1, c11, rs0 * c01));
        float vz = fmaf(rs2, c22, fmaf(rs1, c12, rs0 * c02));
        float d2 = fmaf(vz, vz, fmaf(vy, vy, vx * vx));
        float dd = sqrtf(fmaxf(d2, 1e-12f));
        int node = b * N_ + i;
        int eo = node * K_ + lane;
        idx_o[eo] = j;
        d_o[eo] = dd;
        vec_o[eo * 3 + 0] = vx;
        vec_o[eo * 3 + 1] = vy;
        vec_o[eo * 3 + 2] = vz;
    }
}

// ---------------- bf16 MFMA GEMM: C[128 x 64 tile] = A[16384 x 128] @ Bt^T ----------------
// A fp32 (converted to bf16 in-kernel), Bt bf16 pre-packed [N][K=128].
// K=128 staged entirely in LDS: one sync, 4 K-steps of 16x16x32 MFMA.
__global__ __launch_bounds__(256) void k_gemm_mfma(const float* __restrict__ A,
                                                   const unsigned short* __restrict__ Bt,
                                                   const float* __restrict__ bias,
                                                   const float* __restrict__ resid,
                                                   float* __restrict__ C, int ldc) {
    __shared__ unsigned short As[128][136];  // +8 pad: 272B row stride (2-way banks, free)
    __shared__ unsigned short Bs[64][136];
    int m0 = blockIdx.x * 128;
    int col0 = blockIdx.y * 64;
    int t = threadIdx.x;

    // stage A tile: fp32 -> bf16
#pragma unroll
    for (int it = 0; it < 16; ++it) {
        int id = t + it * 256;         // 0..4095
        int row = id >> 5;             // 0..127
        int c4 = (id & 31) << 2;       // 0..124
        float4 v = *reinterpret_cast<const float4*>(&A[(size_t)(m0 + row) * 128 + c4]);
        ushort4 pk;
        pk.x = f2bf_bits(v.x);
        pk.y = f2bf_bits(v.y);
        pk.z = f2bf_bits(v.z);
        pk.w = f2bf_bits(v.w);
        *reinterpret_cast<ushort4*>(&As[row][c4]) = pk;
    }
    // stage B tile: straight bf16 copy, [n][k]
#pragma unroll
    for (int it = 0; it < 4; ++it) {
        int id = t + it * 256;       // 0..1023
        int n = id >> 4;             // 0..63
        int ck = (id & 15) << 3;     // 0..120
        int4 v = *reinterpret_cast<const int4*>(&Bt[(size_t)(col0 + n) * 128 + ck]);
        *reinterpret_cast<int4*>(&Bs[n][ck]) = v;
    }
    __syncthreads();

    int wave = t >> 6, lane = t & 63;
    int wm = wave >> 1, wn = wave & 1;   // 2x2 waves: 64x32 out each
    int fr16 = lane & 15, ko = lane >> 4;
    f32x4 acc[4][2];
#pragma unroll
    for (int fm = 0; fm < 4; ++fm)
#pragma unroll
        for (int fn = 0; fn < 2; ++fn) acc[fm][fn] = (f32x4){0.f, 0.f, 0.f, 0.f};

#pragma unroll
    for (int ks = 0; ks < 4; ++ks) {
        bf16x8 af[4], bf[2];
#pragma unroll
        for (int fm = 0; fm < 4; ++fm)
            af[fm] = *reinterpret_cast<const bf16x8*>(
                &As[wm * 64 + fm * 16 + fr16][ks * 32 + ko * 8]);
#pragma unroll
        for (int fn = 0; fn < 2; ++fn)
            bf[fn] = *reinterpret_cast<const bf16x8*>(
                &Bs[wn * 32 + fn * 16 + fr16][ks * 32 + ko * 8]);
#pragma unroll
        for (int fm = 0; fm < 4; ++fm)
#pragma unroll
            for (int fn = 0; fn < 2; ++fn)
                acc[fm][fn] = __builtin_amdgcn_mfma_f32_16x16x32_bf16(af[fm], bf[fn],
                                                                      acc[fm][fn], 0, 0, 0);
    }

    // epilogue: C/D layout col = lane&15, row = (lane>>4)*4 + r  [m89]
#pragma unroll
    for (int fm = 0; fm < 4; ++fm) {
        int r0 = m0 + wm * 64 + fm * 16 + ko * 4;
#pragma unroll
        for (int fn = 0; fn < 2; ++fn) {
            int cg = col0 + wn * 32 + fn * 16 + fr16;
#pragma unroll
            for (int r = 0; r < 4; ++r) {
                float val = acc[fm][fn][r];
                if (bias) val += bias[cg];
                if (resid) val += resid[(size_t)(r0 + r) * 128 + cg];
                C[(size_t)(r0 + r) * ldc + cg] = val;
            }
        }
    }
}

// ---------------- per-edge silu + mean (savg) ----------------
__global__ __launch_bounds__(256) void k_edge(const float* __restrict__ UV,
                                              const int* __restrict__ idx,
                                              const float* __restrict__ nd,
                                              const float* __restrict__ w1d,
                                              const float* __restrict__ b1,
                                              float* __restrict__ savg) {
    int g = threadIdx.x >> 4;
    int fc = threadIdx.x & 15;
    int node = blockIdx.x * 16 + g;
    int b = node >> 10;
    int f0 = fc * 8;
    float u[8], wd[8], bb[8], acc[8];
#pragma unroll
    for (int q = 0; q < 8; q += 4) {
        float4 t = *reinterpret_cast<const float4*>(&UV[(size_t)node * 256 + f0 + q]);
        u[q] = t.x; u[q + 1] = t.y; u[q + 2] = t.z; u[q + 3] = t.w;
        float4 t2 = *reinterpret_cast<const float4*>(&w1d[f0 + q]);
        wd[q] = t2.x; wd[q + 1] = t2.y; wd[q + 2] = t2.z; wd[q + 3] = t2.w;
        float4 t3 = *reinterpret_cast<const float4*>(&b1[f0 + q]);
        bb[q] = t3.x; bb[q + 1] = t3.y; bb[q + 2] = t3.z; bb[q + 3] = t3.w;
    }
#pragma unroll
    for (int q = 0; q < 8; ++q) acc[q] = 0.f;
    int ebase = node * K_;
    for (int e = 0; e < K_; ++e) {
        int j = idx[ebase + e];
        float dd = nd[ebase + e];
        const float* vp = &UV[(size_t)(b * N_ + j) * 256 + 128 + f0];
#pragma unroll
        for (int q = 0; q < 8; q += 4) {
            float4 t = *reinterpret_cast<const float4*>(&vp[q]);
            float v4[4] = {t.x, t.y, t.z, t.w};
#pragma unroll
            for (int w = 0; w < 4; ++w) {
                float pre = u[q + w] + v4[w] + fmaf(dd, wd[q + w], bb[q + w]);
                acc[q + w] += silu_f(pre);
            }
        }
    }
    const float inv_k = 1.0f / (float)K_;
#pragma unroll
    for (int q = 0; q < 8; q += 4) {
        float4 o = {acc[q] * inv_k, acc[q + 1] * inv_k, acc[q + 2] * inv_k, acc[q + 3] * inv_k};
        *reinterpret_cast<float4*>(&savg[(size_t)node * 128 + f0 + q]) = o;
    }
}

// ---------------- final head: per-edge weight, delta, output ----------------
__global__ __launch_bounds__(256) void k_final(const float* __restrict__ P,
                                               const int* __restrict__ idx,
                                               const float* __restrict__ nd,
                                               const float* __restrict__ nvec,
                                               const float* __restrict__ A1d,
                                               const float* __restrict__ a1v,
                                               const float* __restrict__ A2v,
                                               const float* __restrict__ a2v,
                                               const float* __restrict__ x,
                                               const float* __restrict__ cell,
                                               float* __restrict__ out) {
    __shared__ float plds[16][256];  // [e][g*16+fc]
    __shared__ float wlds[16][17];
    __shared__ float dclds[16][3];
    int g = threadIdx.x >> 4, fc = threadIdx.x & 15;
    int node = blockIdx.x * 16 + g;
    int b = node >> 10;
    int f0 = fc * 8;
    float pa[8], ad[8], aa[8], a2r[8];
#pragma unroll
    for (int q = 0; q < 8; q += 4) {
        float4 t = *reinterpret_cast<const float4*>(&P[(size_t)node * 256 + f0 + q]);
        pa[q] = t.x; pa[q + 1] = t.y; pa[q + 2] = t.z; pa[q + 3] = t.w;
        float4 t2 = *reinterpret_cast<const float4*>(&A1d[f0 + q]);
        ad[q] = t2.x; ad[q + 1] = t2.y; ad[q + 2] = t2.z; ad[q + 3] = t2.w;
        float4 t3 = *reinterpret_cast<const float4*>(&a1v[f0 + q]);
        aa[q] = t3.x; aa[q + 1] = t3.y; aa[q + 2] = t3.z; aa[q + 3] = t3.w;
        float4 t4 = *reinterpret_cast<const float4*>(&A2v[f0 + q]);
        a2r[q] = t4.x; a2r[q + 1] = t4.y; a2r[q + 2] = t4.z; a2r[q + 3] = t4.w;
    }
    int ebase = node * K_;
    for (int e = 0; e < K_; ++e) {
        int j = idx[ebase + e];
        float dd = nd[ebase + e];
        const float* vp = &P[(size_t)(b * N_ + j) * 256 + 128 + f0];
        float part = 0.f;
#pragma unroll
        for (int q = 0; q < 8; q += 4) {
            float4 t = *reinterpret_cast<const float4*>(&vp[q]);
            float v4[4] = {t.x, t.y, t.z, t.w};
#pragma unroll
            for (int w = 0; w < 4; ++w) {
                float pre = pa[q + w] + v4[w] + fmaf(dd, ad[q + w], aa[q + w]);
                part = fmaf(silu_f(pre), a2r[q + w], part);
            }
        }
        plds[e][(g << 4) | fc] = part;
    }
    __syncthreads();
    {
        int g2 = threadIdx.x >> 4, e2 = threadIdx.x & 15;
        float w = a2v[0];
#pragma unroll
        for (int f2 = 0; f2 < 16; ++f2) w += plds[e2][(g2 << 4) | f2];
        wlds[g2][e2] = w;
    }
    __syncthreads();
    if (threadIdx.x < 48) {
        int gg = threadIdx.x & 15, c = threadIdx.x >> 4;
        int noded = blockIdx.x * 16 + gg;
        float dc = 0.f;
#pragma unroll
        for (int e = 0; e < K_; ++e)
            dc = fmaf(wlds[gg][e], nvec[(size_t)(noded * K_ + e) * 3 + c], dc);
        dclds[gg][c] = dc;
    }
    __syncthreads();
    if (threadIdx.x < 48) {
        int gg = threadIdx.x & 15, c = threadIdx.x >> 4;
        int noded = blockIdx.x * 16 + gg;
        int bb2 = noded >> 10;
        const float* cb = cell + bb2 * 9;
        float c00 = cb[0], c01 = cb[1], c02 = cb[2];
        float c10 = cb[3], c11 = cb[4], c12 = cb[5];
        float c20 = cb[6], c21 = cb[7], c22 = cb[8];
        float det = c00 * (c11 * c22 - c12 * c21) - c01 * (c10 * c22 - c12 * c20) +
                    c02 * (c10 * c21 - c11 * c20);
        float rdet = 1.0f / det;
        float i0c, i1c, i2c;  // column c of inv(cell)
        if (c == 0) {
            i0c = (c11 * c22 - c12 * c21) * rdet;
            i1c = -(c10 * c22 - c12 * c20) * rdet;
            i2c = (c10 * c21 - c11 * c20) * rdet;
        } else if (c == 1) {
            i0c = -(c01 * c22 - c02 * c21) * rdet;
            i1c = (c00 * c22 - c02 * c20) * rdet;
            i2c = -(c00 * c21 - c01 * c20) * rdet;
        } else {
            i0c = (c01 * c12 - c02 * c11) * rdet;
            i1c = -(c00 * c12 - c02 * c10) * rdet;
            i2c = (c00 * c11 - c01 * c10) * rdet;
        }
        float df = dclds[gg][0] * i0c + dclds[gg][1] * i1c + dclds[gg][2] * i2c;
        out[(size_t)noded * 3 + c] = x[(size_t)noded * 3 + c] + df;
    }
}

extern "C" void kernel_launch(void* const* d_in, const int* in_sizes, int n_in,
                              void* d_out, int out_size, void* d_ws, size_t ws_size,
                              hipStream_t stream) {
    (void)in_sizes; (void)n_in; (void)out_size; (void)ws_size;
    const float* cell = (const float*)d_in[0];
    const float* x    = (const float*)d_in[1];
    const int*   z    = (const int*)d_in[2];
    const float* emb  = (const float*)d_in[4];
    const float* W1   = (const float*)d_in[5];
    const float* b1   = (const float*)d_in[6];
    const float* W2   = (const float*)d_in[7];
    const float* b2   = (const float*)d_in[8];
    const float* A1   = (const float*)d_in[9];
    const float* a1   = (const float*)d_in[10];
    const float* A2   = (const float*)d_in[11];
    const float* a2   = (const float*)d_in[12];
    float* out = (float*)d_out;

    char* ws = (char*)d_ws;
    size_t off = 0;
    auto alloc = [&](size_t bytes) {
        void* p = ws + off;
        off = (off + bytes + 255) & ~(size_t)255;
        return p;
    };
    int* idx    = (int*)alloc((size_t)B_ * N_ * K_ * 4);
    float* nd   = (float*)alloc((size_t)B_ * N_ * K_ * 4);
    float* nvec = (float*)alloc((size_t)B_ * N_ * K_ * 3 * 4);
    float* h0   = (float*)alloc((size_t)B_ * N_ * F_ * 4);
    float* h1   = (float*)alloc((size_t)B_ * N_ * F_ * 4);
    float* uv   = (float*)alloc((size_t)B_ * N_ * 256 * 4);
    float* sv   = (float*)alloc((size_t)B_ * N_ * F_ * 4);
    unsigned short* Wt1 = (unsigned short*)alloc((size_t)L_ * 256 * 128 * 2);
    unsigned short* Wt2 = (unsigned short*)alloc((size_t)L_ * 128 * 128 * 2);
    unsigned short* At1 = (unsigned short*)alloc((size_t)256 * 128 * 2);

    int conv_total = L_ * 256 * 128 + L_ * 128 * 128 + 256 * 128;
    k_wconv<<<(conv_total + 255) / 256, 256, 0, stream>>>(W1, W2, A1, Wt1, Wt2, At1);
    k_embed<<<2048, 256, 0, stream>>>(z, emb, h0);
    k_knn<<<4096, 256, 0, stream>>>(x, cell, idx, nvec, nd);

    float* hc = h0;
    float* hn = h1;
    for (int l = 0; l < L_; ++l) {
        k_gemm_mfma<<<dim3(128, 4), 256, 0, stream>>>(hc, Wt1 + (size_t)l * 256 * 128,
                                                      nullptr, nullptr, uv, 256);
        k_edge<<<1024, 256, 0, stream>>>(uv, idx, nd, W1 + (size_t)l * DIN_ * F_ + 256 * F_,
                                         b1 + l * F_, sv);
        k_gemm_mfma<<<dim3(128, 2), 256, 0, stream>>>(sv, Wt2 + (size_t)l * 128 * 128,
                                                      b2 + l * F_, hc, hn, 128);
        float* tmp = hc; hc = hn; hn = tmp;
    }
    k_gemm_mfma<<<dim3(128, 4), 256, 0, stream>>>(hc, At1, nullptr, nullptr, uv, 256);
    k_final<<<1024, 256, 0, stream>>>(uv, idx, nd, nvec, A1 + 256 * F_, a1, A2, a2, x, cell,
                                      out);
}

// Round 3
// 345.988 us; speedup vs baseline: 1.2766x; 1.0057x over previous
//
#include <hip/hip_runtime.h>

#define B_ 16
#define N_ 1024
#define K_ 16
#define F_ 128
#define L_ 4
#define DIN_ 257

typedef __bf16 bf16x8 __attribute__((ext_vector_type(8)));
typedef float f32x4 __attribute__((ext_vector_type(4)));

__device__ __forceinline__ float silu_f(float x) {
    return x / (1.0f + __expf(-x));
}

__device__ __forceinline__ unsigned short f2bf_bits(float f) {
    unsigned u = __builtin_bit_cast(unsigned, f);
    return (unsigned short)((u + 0x7FFFu + ((u >> 16) & 1u)) >> 16);
}

// ---------------- h0 = emb[z] (fp32 + bf16 shadow) ----------------
__global__ __launch_bounds__(256) void k_embed(const int* __restrict__ z,
                                               const float* __restrict__ emb,
                                               float* __restrict__ h,
                                               unsigned short* __restrict__ hbf) {
    int t = blockIdx.x * 256 + threadIdx.x;  // one thread per (node, float4)
    int node = t >> 5;
    int f4 = (t & 31) << 2;
    if (node >= B_ * N_) return;
    int zi = z[node];
    float4 v = *reinterpret_cast<const float4*>(&emb[zi * F_ + f4]);
    *reinterpret_cast<float4*>(&h[node * F_ + f4]) = v;
    ushort4 pk;
    pk.x = f2bf_bits(v.x); pk.y = f2bf_bits(v.y);
    pk.z = f2bf_bits(v.z); pk.w = f2bf_bits(v.w);
    *reinterpret_cast<ushort4*>(&hbf[node * F_ + f4]) = pk;
}

// ---------------- weight pack/convert: fp32 [k][n] -> bf16 [n][k] ----------------
__global__ __launch_bounds__(256) void k_wconv(const float* __restrict__ W1,
                                               const float* __restrict__ W2,
                                               const float* __restrict__ A1,
                                               unsigned short* __restrict__ Wt1,
                                               unsigned short* __restrict__ Wt2,
                                               unsigned short* __restrict__ At1) {
    int id = blockIdx.x * 256 + threadIdx.x;
    if (id < L_ * 256 * 128) {
        int k = id & 127, n = (id >> 7) & 255, l = id >> 15;
        float v = (n < 128) ? W1[(size_t)l * DIN_ * F_ + (size_t)k * F_ + n]
                            : W1[(size_t)l * DIN_ * F_ + (size_t)(128 + k) * F_ + (n - 128)];
        Wt1[id] = f2bf_bits(v);
        return;
    }
    id -= L_ * 256 * 128;
    if (id < L_ * 128 * 128) {
        int k = id & 127, n = (id >> 7) & 127, l = id >> 14;
        Wt2[id] = f2bf_bits(W2[(size_t)l * F_ * F_ + (size_t)k * F_ + n]);
        return;
    }
    id -= L_ * 128 * 128;
    if (id < 256 * 128) {
        int k = id & 127, n = id >> 7;
        float v = (n < 128) ? A1[(size_t)k * 128 + n]
                            : A1[(size_t)(128 + k) * 128 + (n - 128)];
        At1[id] = f2bf_bits(v);
    }
}

// ---------------- periodic KNN: wave per row i ----------------
// Distance arithmetic bit-identical to the validated round-1/2 kernel.
// Selection on u64 keys (hi=d2 bits, lo=(j<<5)|sid): u64 ascending ==
// lexicographic (d2, j, sid) ascending (d2>=0, keys globally unique).
__global__ __launch_bounds__(256) void k_knn(const float* __restrict__ x,
                                             const float* __restrict__ cell,
                                             int* __restrict__ idx_o,
                                             float* __restrict__ vec_o,
                                             float* __restrict__ d_o) {
    __shared__ float fr[N_ * 3];
    int b = blockIdx.x >> 8;            // 256 blocks per batch
    int ib = (blockIdx.x & 255) << 2;   // 4 rows per block (1 per wave)
    const float* xb = x + b * N_ * 3;
    for (int u = threadIdx.x; u < N_ * 3; u += 256) {
        float xv = xb[u];
        fr[u] = xv - floorf(xv);
    }
    __syncthreads();
    int wave = threadIdx.x >> 6;
    int lane = threadIdx.x & 63;
    int i = ib + wave;

    const float* cb = cell + b * 9;
    float c00 = cb[0], c01 = cb[1], c02 = cb[2];
    float c10 = cb[3], c11 = cb[4], c12 = cb[5];
    float c20 = cb[6], c21 = cb[7], c22 = cb[8];
    float fi0 = fr[i * 3 + 0], fi1 = fr[i * 3 + 1], fi2 = fr[i * 3 + 2];

    unsigned long long k[16];
#pragma unroll
    for (int t = 0; t < 16; ++t) {
        int j = t * 64 + lane;
        float r0 = fr[j * 3 + 0] - fi0;
        float r1 = fr[j * 3 + 1] - fi1;
        float r2 = fr[j * 3 + 2] - fi2;
        float s0f = (r0 > 0.f) ? -1.f : 0.f;
        float s1f = (r1 > 0.f) ? -1.f : 0.f;
        float s2f = (r2 > 0.f) ? -1.f : 0.f;
        int sid_base = ((r0 > 0.f) ? 0 : 9) + ((r1 > 0.f) ? 0 : 3) + ((r2 > 0.f) ? 0 : 1);
        float rx0 = r0 + s0f, rx1 = r0 + (s0f + 1.0f);
        float ry0 = r1 + s1f, ry1 = r1 + (s1f + 1.0f);
        float rz0 = r2 + s2f, rz1 = r2 + (s2f + 1.0f);
        float best = 3e38f;
        int bsid = 0;
#pragma unroll
        for (int cbo = 0; cbo < 8; ++cbo) {  // bit2=i0, bit1=i1, bit0=i2 (ascending sid)
            float rs0 = (cbo & 4) ? rx1 : rx0;
            float rs1 = (cbo & 2) ? ry1 : ry0;
            float rs2 = (cbo & 1) ? rz1 : rz0;
            float cx = fmaf(rs2, c20, fmaf(rs1, c10, rs0 * c00));
            float cy = fmaf(rs2, c21, fmaf(rs1, c11, rs0 * c01));
            float cz = fmaf(rs2, c22, fmaf(rs1, c12, rs0 * c02));
            float d2 = fmaf(cz, cz, fmaf(cy, cy, cx * cx));
            int sid = sid_base + ((cbo >> 2) & 1) * 9 + ((cbo >> 1) & 1) * 3 + (cbo & 1);
            if (d2 < best) { best = d2; bsid = sid; }
        }
        if (j == i) best = 3e38f;  // exclude self
        unsigned db = __builtin_bit_cast(unsigned, best);
        k[t] = ((unsigned long long)db << 32) | (unsigned)((j << 5) | bsid);
    }

    // Batcher odd-even mergesort of the 16 lane-local keys (63 CEs).
#define CE_(a, b)                                              \
    {                                                          \
        unsigned long long x_ = k[a], y_ = k[b];               \
        bool s_ = y_ < x_;                                     \
        k[a] = s_ ? y_ : x_;                                   \
        k[b] = s_ ? x_ : y_;                                   \
    }
    CE_(0,1) CE_(2,3) CE_(4,5) CE_(6,7) CE_(8,9) CE_(10,11) CE_(12,13) CE_(14,15)
    CE_(0,2) CE_(1,3) CE_(4,6) CE_(5,7) CE_(8,10) CE_(9,11) CE_(12,14) CE_(13,15)
    CE_(1,2) CE_(5,6) CE_(9,10) CE_(13,14)
    CE_(0,4) CE_(1,5) CE_(2,6) CE_(3,7) CE_(8,12) CE_(9,13) CE_(10,14) CE_(11,15)
    CE_(2,4) CE_(3,5) CE_(10,12) CE_(11,13)
    CE_(1,2) CE_(3,4) CE_(5,6) CE_(9,10) CE_(11,12) CE_(13,14)
    CE_(0,8) CE_(1,9) CE_(2,10) CE_(3,11) CE_(4,12) CE_(5,13) CE_(6,14) CE_(7,15)
    CE_(4,8) CE_(5,9) CE_(6,10) CE_(7,11)
    CE_(2,4) CE_(3,5) CE_(6,8) CE_(7,9) CE_(10,12) CE_(11,13)
    CE_(1,2) CE_(3,4) CE_(5,6) CE_(7,8) CE_(9,10) CE_(11,12) CE_(13,14)
#undef CE_

    // 16 extraction rounds: wave-min of sorted-list heads; winner shifts.
    unsigned long long sel = 0;
    for (int r = 0; r < 16; ++r) {
        unsigned long long m = k[0];
#pragma unroll
        for (int off = 32; off >= 1; off >>= 1) {
            unsigned long long o = __shfl_xor(m, off);
            if (o < m) m = o;
        }
        if (k[0] == m) {  // unique winner (keys globally distinct)
#pragma unroll
            for (int t = 0; t < 15; ++t) k[t] = k[t + 1];
            k[15] = ~0ull;
        }
        if (lane == r) sel = m;
    }

    if (lane < 16) {
        unsigned pk = (unsigned)sel;
        int j = pk >> 5, sid = pk & 31;
        int s0 = sid / 9 - 1, s1 = (sid / 3) % 3 - 1, s2 = sid % 3 - 1;
        float rs0 = (fr[j * 3 + 0] - fi0) + (float)s0;
        float rs1 = (fr[j * 3 + 1] - fi1) + (float)s1;
        float rs2 = (fr[j * 3 + 2] - fi2) + (float)s2;
        float vx = fmaf(rs2, c20, fmaf(rs1, c10, rs0 * c00));
        float vy = fmaf(rs2, c21, fmaf(rs1, c11, rs0 * c01));
        float vz = fmaf(rs2, c22, fmaf(rs1, c12, rs0 * c02));
        float d2 = fmaf(vz, vz, fmaf(vy, vy, vx * vx));
        float dd = sqrtf(fmaxf(d2, 1e-12f));
        int node = b * N_ + i;
        int eo = node * K_ + lane;
        idx_o[eo] = j;
        d_o[eo] = dd;
        vec_o[eo * 3 + 0] = vx;
        vec_o[eo * 3 + 1] = vy;
        vec_o[eo * 3 + 2] = vz;
    }
}

// ---------------- register-direct bf16 MFMA GEMM (no LDS, no barriers) ----------------
// One wave = 32x32 output tile. A bf16 [M][128], Bt bf16 [N][128], both
// L2-resident; fragments loaded straight to registers. K=128 = 4 MFMA steps.
template <int LOG_NT>
__global__ __launch_bounds__(256) void k_wgemm(const unsigned short* __restrict__ A,
                                               const unsigned short* __restrict__ Bt,
                                               const float* __restrict__ bias,
                                               const float* __restrict__ resid,
                                               float* __restrict__ C, int ldc,
                                               unsigned short* __restrict__ Cbf) {
    constexpr int NT = 1 << LOG_NT;
    int wave = threadIdx.x >> 6, lane = threadIdx.x & 63;
    int tile = blockIdx.x * 4 + wave;
    int mt = tile >> LOG_NT, nt = tile & (NT - 1);
    int fr16 = lane & 15, ko = lane >> 4;
    const unsigned short* Ap = A + (size_t)(mt * 32 + fr16) * 128 + ko * 8;
    const unsigned short* Bp = Bt + (size_t)(nt * 32 + fr16) * 128 + ko * 8;

    bf16x8 a0[4], a1[4], b0[4], b1[4];
#pragma unroll
    for (int ks = 0; ks < 4; ++ks) {
        a0[ks] = *reinterpret_cast<const bf16x8*>(Ap + ks * 32);
        a1[ks] = *reinterpret_cast<const bf16x8*>(Ap + 16 * 128 + ks * 32);
        b0[ks] = *reinterpret_cast<const bf16x8*>(Bp + ks * 32);
        b1[ks] = *reinterpret_cast<const bf16x8*>(Bp + 16 * 128 + ks * 32);
    }
    f32x4 acc00 = {0.f, 0.f, 0.f, 0.f}, acc01 = acc00, acc10 = acc00, acc11 = acc00;
#pragma unroll
    for (int ks = 0; ks < 4; ++ks) {
        acc00 = __builtin_amdgcn_mfma_f32_16x16x32_bf16(a0[ks], b0[ks], acc00, 0, 0, 0);
        acc01 = __builtin_amdgcn_mfma_f32_16x16x32_bf16(a0[ks], b1[ks], acc01, 0, 0, 0);
        acc10 = __builtin_amdgcn_mfma_f32_16x16x32_bf16(a1[ks], b0[ks], acc10, 0, 0, 0);
        acc11 = __builtin_amdgcn_mfma_f32_16x16x32_bf16(a1[ks], b1[ks], acc11, 0, 0, 0);
    }

    // C/D layout: col = lane&15, row = (lane>>4)*4 + r  [m89]
    int mrow = mt * 32 + ko * 4;
    int cbase = nt * 32 + fr16;
#define EPI_(FM, FN, ACC)                                                    \
    {                                                                        \
        int cc = cbase + FN * 16;                                            \
        float bv = bias ? bias[cc] : 0.f;                                    \
        _Pragma("unroll") for (int r = 0; r < 4; ++r) {                      \
            int row = mrow + FM * 16 + r;                                    \
            float val = ACC[r] + bv;                                         \
            if (resid) val += resid[(size_t)row * 128 + cc];                 \
            C[(size_t)row * ldc + cc] = val;                                 \
            if (Cbf) Cbf[(size_t)row * 128 + cc] = f2bf_bits(val);           \
        }                                                                    \
    }
    EPI_(0, 0, acc00) EPI_(0, 1, acc01) EPI_(1, 0, acc10) EPI_(1, 1, acc11)
#undef EPI_
}

// ---------------- per-edge silu + mean -> bf16 savg ----------------
__global__ __launch_bounds__(256) void k_edge(const float* __restrict__ UV,
                                              const int* __restrict__ idx,
                                              const float* __restrict__ nd,
                                              const float* __restrict__ w1d,
                                              const float* __restrict__ b1,
                                              unsigned short* __restrict__ savg) {
    int g = threadIdx.x >> 4;
    int fc = threadIdx.x & 15;
    int node = blockIdx.x * 16 + g;
    int b = node >> 10;
    int f0 = fc * 8;
    float u[8], wd[8], bb[8], acc[8];
#pragma unroll
    for (int q = 0; q < 8; q += 4) {
        float4 t = *reinterpret_cast<const float4*>(&UV[(size_t)node * 256 + f0 + q]);
        u[q] = t.x; u[q + 1] = t.y; u[q + 2] = t.z; u[q + 3] = t.w;
        float4 t2 = *reinterpret_cast<const float4*>(&w1d[f0 + q]);
        wd[q] = t2.x; wd[q + 1] = t2.y; wd[q + 2] = t2.z; wd[q + 3] = t2.w;
        float4 t3 = *reinterpret_cast<const float4*>(&b1[f0 + q]);
        bb[q] = t3.x; bb[q + 1] = t3.y; bb[q + 2] = t3.z; bb[q + 3] = t3.w;
    }
#pragma unroll
    for (int q = 0; q < 8; ++q) acc[q] = 0.f;
    int ebase = node * K_;
    for (int e = 0; e < K_; ++e) {
        int j = idx[ebase + e];
        float dd = nd[ebase + e];
        const float* vp = &UV[(size_t)(b * N_ + j) * 256 + 128 + f0];
#pragma unroll
        for (int q = 0; q < 8; q += 4) {
            float4 t = *reinterpret_cast<const float4*>(&vp[q]);
            float v4[4] = {t.x, t.y, t.z, t.w};
#pragma unroll
            for (int w = 0; w < 4; ++w) {
                float pre = u[q + w] + v4[w] + fmaf(dd, wd[q + w], bb[q + w]);
                acc[q + w] += silu_f(pre);
            }
        }
    }
    const float inv_k = 1.0f / (float)K_;
    unsigned ow[4];
#pragma unroll
    for (int q = 0; q < 4; ++q)
        ow[q] = (unsigned)f2bf_bits(acc[2 * q] * inv_k) |
                ((unsigned)f2bf_bits(acc[2 * q + 1] * inv_k) << 16);
    *reinterpret_cast<int4*>(&savg[(size_t)node * 128 + f0]) =
        make_int4(ow[0], ow[1], ow[2], ow[3]);
}

// ---------------- final head: per-edge weight, delta, output ----------------
__global__ __launch_bounds__(256) void k_final(const float* __restrict__ P,
                                               const int* __restrict__ idx,
                                               const float* __restrict__ nd,
                                               const float* __restrict__ nvec,
                                               const float* __restrict__ A1d,
                                               const float* __restrict__ a1v,
                                               const float* __restrict__ A2v,
                                               const float* __restrict__ a2v,
                                               const float* __restrict__ x,
                                               const float* __restrict__ cell,
                                               float* __restrict__ out) {
    __shared__ float plds[16][256];  // [e][g*16+fc]
    __shared__ float wlds[16][17];
    __shared__ float dclds[16][3];
    int g = threadIdx.x >> 4, fc = threadIdx.x & 15;
    int node = blockIdx.x * 16 + g;
    int b = node >> 10;
    int f0 = fc * 8;
    float pa[8], ad[8], aa[8], a2r[8];
#pragma unroll
    for (int q = 0; q < 8; q += 4) {
        float4 t = *reinterpret_cast<const float4*>(&P[(size_t)node * 256 + f0 + q]);
        pa[q] = t.x; pa[q + 1] = t.y; pa[q + 2] = t.z; pa[q + 3] = t.w;
        float4 t2 = *reinterpret_cast<const float4*>(&A1d[f0 + q]);
        ad[q] = t2.x; ad[q + 1] = t2.y; ad[q + 2] = t2.z; ad[q + 3] = t2.w;
        float4 t3 = *reinterpret_cast<const float4*>(&a1v[f0 + q]);
        aa[q] = t3.x; aa[q + 1] = t3.y; aa[q + 2] = t3.z; aa[q + 3] = t3.w;
        float4 t4 = *reinterpret_cast<const float4*>(&A2v[f0 + q]);
        a2r[q] = t4.x; a2r[q + 1] = t4.y; a2r[q + 2] = t4.z; a2r[q + 3] = t4.w;
    }
    int ebase = node * K_;
    for (int e = 0; e < K_; ++e) {
        int j = idx[ebase + e];
        float dd = nd[ebase + e];
        const float* vp = &P[(size_t)(b * N_ + j) * 256 + 128 + f0];
        float part = 0.f;
#pragma unroll
        for (int q = 0; q < 8; q += 4) {
            float4 t = *reinterpret_cast<const float4*>(&vp[q]);
            float v4[4] = {t.x, t.y, t.z, t.w};
#pragma unroll
            for (int w = 0; w < 4; ++w) {
                float pre = pa[q + w] + v4[w] + fmaf(dd, ad[q + w], aa[q + w]);
                part = fmaf(silu_f(pre), a2r[q + w], part);
            }
        }
        plds[e][(g << 4) | fc] = part;
    }
    __syncthreads();
    {
        int g2 = threadIdx.x >> 4, e2 = threadIdx.x & 15;
        float w = a2v[0];
#pragma unroll
        for (int f2 = 0; f2 < 16; ++f2) w += plds[e2][(g2 << 4) | f2];
        wlds[g2][e2] = w;
    }
    __syncthreads();
    if (threadIdx.x < 48) {
        int gg = threadIdx.x & 15, c = threadIdx.x >> 4;
        int noded = blockIdx.x * 16 + gg;
        float dc = 0.f;
#pragma unroll
        for (int e = 0; e < K_; ++e)
            dc = fmaf(wlds[gg][e], nvec[(size_t)(noded * K_ + e) * 3 + c], dc);
        dclds[gg][c] = dc;
    }
    __syncthreads();
    if (threadIdx.x < 48) {
        int gg = threadIdx.x & 15, c = threadIdx.x >> 4;
        int noded = blockIdx.x * 16 + gg;
        int bb2 = noded >> 10;
        const float* cb = cell + bb2 * 9;
        float c00 = cb[0], c01 = cb[1], c02 = cb[2];
        float c10 = cb[3], c11 = cb[4], c12 = cb[5];
        float c20 = cb[6], c21 = cb[7], c22 = cb[8];
        float det = c00 * (c11 * c22 - c12 * c21) - c01 * (c10 * c22 - c12 * c20) +
                    c02 * (c10 * c21 - c11 * c20);
        float rdet = 1.0f / det;
        float i0c, i1c, i2c;  // column c of inv(cell)
        if (c == 0) {
            i0c = (c11 * c22 - c12 * c21) * rdet;
            i1c = -(c10 * c22 - c12 * c20) * rdet;
            i2c = (c10 * c21 - c11 * c20) * rdet;
        } else if (c == 1) {
            i0c = -(c01 * c22 - c02 * c21) * rdet;
            i1c = (c00 * c22 - c02 * c20) * rdet;
            i2c = -(c00 * c21 - c01 * c20) * rdet;
        } else {
            i0c = (c01 * c12 - c02 * c11) * rdet;
            i1c = -(c00 * c12 - c02 * c10) * rdet;
            i2c = (c00 * c11 - c01 * c10) * rdet;
        }
        float df = dclds[gg][0] * i0c + dclds[gg][1] * i1c + dclds[gg][2] * i2c;
        out[(size_t)noded * 3 + c] = x[(size_t)noded * 3 + c] + df;
    }
}

extern "C" void kernel_launch(void* const* d_in, const int* in_sizes, int n_in,
                              void* d_out, int out_size, void* d_ws, size_t ws_size,
                              hipStream_t stream) {
    (void)in_sizes; (void)n_in; (void)out_size; (void)ws_size;
    const float* cell = (const float*)d_in[0];
    const float* x    = (const float*)d_in[1];
    const int*   z    = (const int*)d_in[2];
    const float* emb  = (const float*)d_in[4];
    const float* W1   = (const float*)d_in[5];
    const float* b1   = (const float*)d_in[6];
    const float* W2   = (const float*)d_in[7];
    const float* b2   = (const float*)d_in[8];
    const float* A1   = (const float*)d_in[9];
    const float* a1   = (const float*)d_in[10];
    const float* A2   = (const float*)d_in[11];
    const float* a2   = (const float*)d_in[12];
    float* out = (float*)d_out;

    char* ws = (char*)d_ws;
    size_t off = 0;
    auto alloc = [&](size_t bytes) {
        void* p = ws + off;
        off = (off + bytes + 255) & ~(size_t)255;
        return p;
    };
    int* idx    = (int*)alloc((size_t)B_ * N_ * K_ * 4);
    float* nd   = (float*)alloc((size_t)B_ * N_ * K_ * 4);
    float* nvec = (float*)alloc((size_t)B_ * N_ * K_ * 3 * 4);
    float* h0   = (float*)alloc((size_t)B_ * N_ * F_ * 4);
    float* h1   = (float*)alloc((size_t)B_ * N_ * F_ * 4);
    float* uv   = (float*)alloc((size_t)B_ * N_ * 256 * 4);
    unsigned short* hbf  = (unsigned short*)alloc((size_t)B_ * N_ * F_ * 2);
    unsigned short* svbf = (unsigned short*)alloc((size_t)B_ * N_ * F_ * 2);
    unsigned short* Wt1 = (unsigned short*)alloc((size_t)L_ * 256 * 128 * 2);
    unsigned short* Wt2 = (unsigned short*)alloc((size_t)L_ * 128 * 128 * 2);
    unsigned short* At1 = (unsigned short*)alloc((size_t)256 * 128 * 2);

    int conv_total = L_ * 256 * 128 + L_ * 128 * 128 + 256 * 128;
    k_wconv<<<(conv_total + 255) / 256, 256, 0, stream>>>(W1, W2, A1, Wt1, Wt2, At1);
    k_embed<<<2048, 256, 0, stream>>>(z, emb, h0, hbf);
    k_knn<<<4096, 256, 0, stream>>>(x, cell, idx, nvec, nd);

    float* hc = h0;
    float* hn = h1;
    for (int l = 0; l < L_; ++l) {
        k_wgemm<3><<<1024, 256, 0, stream>>>(hbf, Wt1 + (size_t)l * 256 * 128, nullptr,
                                             nullptr, uv, 256, nullptr);
        k_edge<<<1024, 256, 0, stream>>>(uv, idx, nd, W1 + (size_t)l * DIN_ * F_ + 256 * F_,
                                         b1 + l * F_, svbf);
        k_wgemm<2><<<512, 256, 0, stream>>>(svbf, Wt2 + (size_t)l * 128 * 128, b2 + l * F_,
                                            hc, hn, 128, hbf);
        float* tmp = hc; hc = hn; hn = tmp;
    }
    k_wgemm<3><<<1024, 256, 0, stream>>>(hbf, At1, nullptr, nullptr, uv, 256, nullptr);
    k_final<<<1024, 256, 0, stream>>>(uv, idx, nd, nvec, A1 + 256 * F_, a1, A2, a2, x, cell,
                                      out);
}

// Round 4
// 270.250 us; speedup vs baseline: 1.6343x; 1.2803x over previous
//
#include <hip/hip_runtime.h>

#define B_ 16
#define N_ 1024
#define K_ 16
#define F_ 128
#define L_ 4
#define DIN_ 257

typedef __bf16 bf16x8 __attribute__((ext_vector_type(8)));
typedef float f32x4 __attribute__((ext_vector_type(4)));

__device__ __forceinline__ float silu_f(float x) {
    return x / (1.0f + __expf(-x));
}

__device__ __forceinline__ unsigned short f2bf_bits(float f) {
    unsigned u = __builtin_bit_cast(unsigned, f);
    return (unsigned short)((u + 0x7FFFu + ((u >> 16) & 1u)) >> 16);
}

// ---------------- h0 = emb[z] (fp32 + bf16 shadow) ----------------
__global__ __launch_bounds__(256) void k_embed(const int* __restrict__ z,
                                               const float* __restrict__ emb,
                                               float* __restrict__ h,
                                               unsigned short* __restrict__ hbf) {
    int t = blockIdx.x * 256 + threadIdx.x;  // one thread per (node, float4)
    int node = t >> 5;
    int f4 = (t & 31) << 2;
    if (node >= B_ * N_) return;
    int zi = z[node];
    float4 v = *reinterpret_cast<const float4*>(&emb[zi * F_ + f4]);
    *reinterpret_cast<float4*>(&h[node * F_ + f4]) = v;
    ushort4 pk;
    pk.x = f2bf_bits(v.x); pk.y = f2bf_bits(v.y);
    pk.z = f2bf_bits(v.z); pk.w = f2bf_bits(v.w);
    *reinterpret_cast<ushort4*>(&hbf[node * F_ + f4]) = pk;
}

// ---------------- weight pack/convert: fp32 [k][n] -> bf16 [n][k] ----------------
__global__ __launch_bounds__(256) void k_wconv(const float* __restrict__ W1,
                                               const float* __restrict__ W2,
                                               const float* __restrict__ A1,
                                               unsigned short* __restrict__ Wt1,
                                               unsigned short* __restrict__ Wt2,
                                               unsigned short* __restrict__ At1) {
    int id = blockIdx.x * 256 + threadIdx.x;
    if (id < L_ * 256 * 128) {
        int k = id & 127, n = (id >> 7) & 255, l = id >> 15;
        float v = (n < 128) ? W1[(size_t)l * DIN_ * F_ + (size_t)k * F_ + n]
                            : W1[(size_t)l * DIN_ * F_ + (size_t)(128 + k) * F_ + (n - 128)];
        Wt1[id] = f2bf_bits(v);
        return;
    }
    id -= L_ * 256 * 128;
    if (id < L_ * 128 * 128) {
        int k = id & 127, n = (id >> 7) & 127, l = id >> 14;
        Wt2[id] = f2bf_bits(W2[(size_t)l * F_ * F_ + (size_t)k * F_ + n]);
        return;
    }
    id -= L_ * 128 * 128;
    if (id < 256 * 128) {
        int k = id & 127, n = id >> 7;
        float v = (n < 128) ? A1[(size_t)k * 128 + n]
                            : A1[(size_t)(128 + k) * 128 + (n - 128)];
        At1[id] = f2bf_bits(v);
    }
}

// ---------------- periodic KNN: wave per row i (unchanged, validated) ----------------
__global__ __launch_bounds__(256) void k_knn(const float* __restrict__ x,
                                             const float* __restrict__ cell,
                                             int* __restrict__ idx_o,
                                             float* __restrict__ vec_o,
                                             float* __restrict__ d_o) {
    __shared__ float fr[N_ * 3];
    int b = blockIdx.x >> 8;            // 256 blocks per batch
    int ib = (blockIdx.x & 255) << 2;   // 4 rows per block (1 per wave)
    const float* xb = x + b * N_ * 3;
    for (int u = threadIdx.x; u < N_ * 3; u += 256) {
        float xv = xb[u];
        fr[u] = xv - floorf(xv);
    }
    __syncthreads();
    int wave = threadIdx.x >> 6;
    int lane = threadIdx.x & 63;
    int i = ib + wave;

    const float* cb = cell + b * 9;
    float c00 = cb[0], c01 = cb[1], c02 = cb[2];
    float c10 = cb[3], c11 = cb[4], c12 = cb[5];
    float c20 = cb[6], c21 = cb[7], c22 = cb[8];
    float fi0 = fr[i * 3 + 0], fi1 = fr[i * 3 + 1], fi2 = fr[i * 3 + 2];

    unsigned long long k[16];
#pragma unroll
    for (int t = 0; t < 16; ++t) {
        int j = t * 64 + lane;
        float r0 = fr[j * 3 + 0] - fi0;
        float r1 = fr[j * 3 + 1] - fi1;
        float r2 = fr[j * 3 + 2] - fi2;
        float s0f = (r0 > 0.f) ? -1.f : 0.f;
        float s1f = (r1 > 0.f) ? -1.f : 0.f;
        float s2f = (r2 > 0.f) ? -1.f : 0.f;
        int sid_base = ((r0 > 0.f) ? 0 : 9) + ((r1 > 0.f) ? 0 : 3) + ((r2 > 0.f) ? 0 : 1);
        float rx0 = r0 + s0f, rx1 = r0 + (s0f + 1.0f);
        float ry0 = r1 + s1f, ry1 = r1 + (s1f + 1.0f);
        float rz0 = r2 + s2f, rz1 = r2 + (s2f + 1.0f);
        float best = 3e38f;
        int bsid = 0;
#pragma unroll
        for (int cbo = 0; cbo < 8; ++cbo) {  // bit2=i0, bit1=i1, bit0=i2 (ascending sid)
            float rs0 = (cbo & 4) ? rx1 : rx0;
            float rs1 = (cbo & 2) ? ry1 : ry0;
            float rs2 = (cbo & 1) ? rz1 : rz0;
            float cx = fmaf(rs2, c20, fmaf(rs1, c10, rs0 * c00));
            float cy = fmaf(rs2, c21, fmaf(rs1, c11, rs0 * c01));
            float cz = fmaf(rs2, c22, fmaf(rs1, c12, rs0 * c02));
            float d2 = fmaf(cz, cz, fmaf(cy, cy, cx * cx));
            int sid = sid_base + ((cbo >> 2) & 1) * 9 + ((cbo >> 1) & 1) * 3 + (cbo & 1);
            if (d2 < best) { best = d2; bsid = sid; }
        }
        if (j == i) best = 3e38f;  // exclude self
        unsigned db = __builtin_bit_cast(unsigned, best);
        k[t] = ((unsigned long long)db << 32) | (unsigned)((j << 5) | bsid);
    }

    // Batcher odd-even mergesort of the 16 lane-local keys (63 CEs).
#define CE_(a, b)                                              \
    {                                                          \
        unsigned long long x_ = k[a], y_ = k[b];               \
        bool s_ = y_ < x_;                                     \
        k[a] = s_ ? y_ : x_;                                   \
        k[b] = s_ ? x_ : y_;                                   \
    }
    CE_(0,1) CE_(2,3) CE_(4,5) CE_(6,7) CE_(8,9) CE_(10,11) CE_(12,13) CE_(14,15)
    CE_(0,2) CE_(1,3) CE_(4,6) CE_(5,7) CE_(8,10) CE_(9,11) CE_(12,14) CE_(13,15)
    CE_(1,2) CE_(5,6) CE_(9,10) CE_(13,14)
    CE_(0,4) CE_(1,5) CE_(2,6) CE_(3,7) CE_(8,12) CE_(9,13) CE_(10,14) CE_(11,15)
    CE_(2,4) CE_(3,5) CE_(10,12) CE_(11,13)
    CE_(1,2) CE_(3,4) CE_(5,6) CE_(9,10) CE_(11,12) CE_(13,14)
    CE_(0,8) CE_(1,9) CE_(2,10) CE_(3,11) CE_(4,12) CE_(5,13) CE_(6,14) CE_(7,15)
    CE_(4,8) CE_(5,9) CE_(6,10) CE_(7,11)
    CE_(2,4) CE_(3,5) CE_(6,8) CE_(7,9) CE_(10,12) CE_(11,13)
    CE_(1,2) CE_(3,4) CE_(5,6) CE_(7,8) CE_(9,10) CE_(11,12) CE_(13,14)
#undef CE_

    // 16 extraction rounds: wave-min of sorted-list heads; winner shifts.
    unsigned long long sel = 0;
    for (int r = 0; r < 16; ++r) {
        unsigned long long m = k[0];
#pragma unroll
        for (int off = 32; off >= 1; off >>= 1) {
            unsigned long long o = __shfl_xor(m, off);
            if (o < m) m = o;
        }
        if (k[0] == m) {  // unique winner (keys globally distinct)
#pragma unroll
            for (int t = 0; t < 15; ++t) k[t] = k[t + 1];
            k[15] = ~0ull;
        }
        if (lane == r) sel = m;
    }

    if (lane < 16) {
        unsigned pk = (unsigned)sel;
        int j = pk >> 5, sid = pk & 31;
        int s0 = sid / 9 - 1, s1 = (sid / 3) % 3 - 1, s2 = sid % 3 - 1;
        float rs0 = (fr[j * 3 + 0] - fi0) + (float)s0;
        float rs1 = (fr[j * 3 + 1] - fi1) + (float)s1;
        float rs2 = (fr[j * 3 + 2] - fi2) + (float)s2;
        float vx = fmaf(rs2, c20, fmaf(rs1, c10, rs0 * c00));
        float vy = fmaf(rs2, c21, fmaf(rs1, c11, rs0 * c01));
        float vz = fmaf(rs2, c22, fmaf(rs1, c12, rs0 * c02));
        float d2 = fmaf(vz, vz, fmaf(vy, vy, vx * vx));
        float dd = sqrtf(fmaxf(d2, 1e-12f));
        int node = b * N_ + i;
        int eo = node * K_ + lane;
        idx_o[eo] = j;
        d_o[eo] = dd;
        vec_o[eo * 3 + 0] = vx;
        vec_o[eo * 3 + 1] = vy;
        vec_o[eo * 3 + 2] = vz;
    }
}

// ---------------- register-direct bf16 MFMA GEMM (layer-0 G1 only) ----------------
template <int LOG_NT>
__global__ __launch_bounds__(256) void k_wgemm(const unsigned short* __restrict__ A,
                                               const unsigned short* __restrict__ Bt,
                                               float* __restrict__ C, int ldc) {
    constexpr int NT = 1 << LOG_NT;
    int wave = threadIdx.x >> 6, lane = threadIdx.x & 63;
    int tile = blockIdx.x * 4 + wave;
    int mt = tile >> LOG_NT, nt = tile & (NT - 1);
    int fr16 = lane & 15, ko = lane >> 4;
    const unsigned short* Ap = A + (size_t)(mt * 32 + fr16) * 128 + ko * 8;
    const unsigned short* Bp = Bt + (size_t)(nt * 32 + fr16) * 128 + ko * 8;

    bf16x8 a0[4], a1[4], b0[4], b1[4];
#pragma unroll
    for (int ks = 0; ks < 4; ++ks) {
        a0[ks] = *reinterpret_cast<const bf16x8*>(Ap + ks * 32);
        a1[ks] = *reinterpret_cast<const bf16x8*>(Ap + 16 * 128 + ks * 32);
        b0[ks] = *reinterpret_cast<const bf16x8*>(Bp + ks * 32);
        b1[ks] = *reinterpret_cast<const bf16x8*>(Bp + 16 * 128 + ks * 32);
    }
    f32x4 acc00 = {0.f, 0.f, 0.f, 0.f}, acc01 = acc00, acc10 = acc00, acc11 = acc00;
#pragma unroll
    for (int ks = 0; ks < 4; ++ks) {
        acc00 = __builtin_amdgcn_mfma_f32_16x16x32_bf16(a0[ks], b0[ks], acc00, 0, 0, 0);
        acc01 = __builtin_amdgcn_mfma_f32_16x16x32_bf16(a0[ks], b1[ks], acc01, 0, 0, 0);
        acc10 = __builtin_amdgcn_mfma_f32_16x16x32_bf16(a1[ks], b0[ks], acc10, 0, 0, 0);
        acc11 = __builtin_amdgcn_mfma_f32_16x16x32_bf16(a1[ks], b1[ks], acc11, 0, 0, 0);
    }
    int mrow = mt * 32 + ko * 4;
    int cbase = nt * 32 + fr16;
#define EPI_(FM, FN, ACC)                                                    \
    {                                                                        \
        int cc = cbase + FN * 16;                                            \
        _Pragma("unroll") for (int r = 0; r < 4; ++r) {                      \
            int row = mrow + FM * 16 + r;                                    \
            C[(size_t)row * ldc + cc] = ACC[r];                              \
        }                                                                    \
    }
    EPI_(0, 0, acc00) EPI_(0, 1, acc01) EPI_(1, 0, acc10) EPI_(1, 1, acc11)
#undef EPI_
}

// ---------------- fused layer: edge-silu-mean + W2 GEMM + resid + next W1 GEMM ----------------
// 32 nodes per block, 256 threads (4 waves). Numerics identical to the
// k_edge / k_wgemm<2> / k_wgemm<3> chain of round 3.
__global__ __launch_bounds__(256) void k_layer(const float* __restrict__ UVin,
                                               const int* __restrict__ idx,
                                               const float* __restrict__ nd,
                                               const float* __restrict__ w1d,
                                               const float* __restrict__ b1l,
                                               const unsigned short* __restrict__ W2t,
                                               const float* __restrict__ b2l,
                                               float* __restrict__ h,
                                               const unsigned short* __restrict__ W1n,
                                               float* __restrict__ UVout) {
    __shared__ unsigned short svl[32][136];  // savg bf16
    __shared__ unsigned short hbl[32][136];  // h' bf16
    __shared__ int ilds[512];
    __shared__ float dlds[512];
    int tid = threadIdx.x;
    // XCD-friendly remap: the 32 blocks of one batch share blockIdx%8.
    int gb = blockIdx.x;
    int batch = (gb & 7) + 8 * (gb >> 8);
    int ib = (gb >> 3) & 31;
    int node0 = batch * N_ + ib * 32;
    int bbase = batch * N_;

    ilds[tid] = idx[node0 * K_ + tid];
    ilds[tid + 256] = idx[node0 * K_ + tid + 256];
    dlds[tid] = nd[node0 * K_ + tid];
    dlds[tid + 256] = nd[node0 * K_ + tid + 256];
    __syncthreads();

    // ---- edge phase: savg = mean_e silu(u_i + v_j + d*w1d + b1) ----
#pragma unroll
    for (int it = 0; it < 2; ++it) {
        int tsk = it * 256 + tid;
        int gn = tsk >> 4, fc = tsk & 15, f0 = fc << 3;
        int node = node0 + gn;
        float u[8], wd[8], bb[8], acc[8];
#pragma unroll
        for (int q = 0; q < 8; q += 4) {
            float4 t = *reinterpret_cast<const float4*>(&UVin[(size_t)node * 256 + f0 + q]);
            u[q] = t.x; u[q + 1] = t.y; u[q + 2] = t.z; u[q + 3] = t.w;
            float4 t2 = *reinterpret_cast<const float4*>(&w1d[f0 + q]);
            wd[q] = t2.x; wd[q + 1] = t2.y; wd[q + 2] = t2.z; wd[q + 3] = t2.w;
            float4 t3 = *reinterpret_cast<const float4*>(&b1l[f0 + q]);
            bb[q] = t3.x; bb[q + 1] = t3.y; bb[q + 2] = t3.z; bb[q + 3] = t3.w;
        }
#pragma unroll
        for (int q = 0; q < 8; ++q) acc[q] = 0.f;
        for (int e = 0; e < K_; ++e) {
            int j = ilds[gn * K_ + e];
            float dd = dlds[gn * K_ + e];
            const float* vp = &UVin[(size_t)(bbase + j) * 256 + 128 + f0];
#pragma unroll
            for (int q = 0; q < 8; q += 4) {
                float4 t = *reinterpret_cast<const float4*>(&vp[q]);
                float v4[4] = {t.x, t.y, t.z, t.w};
#pragma unroll
                for (int w = 0; w < 4; ++w) {
                    float pre = u[q + w] + v4[w] + fmaf(dd, wd[q + w], bb[q + w]);
                    acc[q + w] += silu_f(pre);
                }
            }
        }
        const float inv_k = 1.0f / (float)K_;
        unsigned ow[4];
#pragma unroll
        for (int q = 0; q < 4; ++q)
            ow[q] = (unsigned)f2bf_bits(acc[2 * q] * inv_k) |
                    ((unsigned)f2bf_bits(acc[2 * q + 1] * inv_k) << 16);
        *reinterpret_cast<int4*>(&svl[gn][f0]) = make_int4(ow[0], ow[1], ow[2], ow[3]);
    }
    __syncthreads();

    int wave = tid >> 6, lane = tid & 63;
    int fr16 = lane & 15, ko = lane >> 4;

    // ---- GEMM2: h' = savg @ W2 + b2 + h; write h (global) + hbl (LDS bf16) ----
    {
        const unsigned short* Bp = W2t + (size_t)(wave * 32 + fr16) * 128 + ko * 8;
        bf16x8 a0[4], a1[4], b0[4], b1f[4];
#pragma unroll
        for (int ks = 0; ks < 4; ++ks) {
            a0[ks] = *reinterpret_cast<const bf16x8*>(&svl[fr16][ks * 32 + ko * 8]);
            a1[ks] = *reinterpret_cast<const bf16x8*>(&svl[fr16 + 16][ks * 32 + ko * 8]);
            b0[ks] = *reinterpret_cast<const bf16x8*>(Bp + ks * 32);
            b1f[ks] = *reinterpret_cast<const bf16x8*>(Bp + 16 * 128 + ks * 32);
        }
        f32x4 acc00 = {0.f, 0.f, 0.f, 0.f}, acc01 = acc00, acc10 = acc00, acc11 = acc00;
#pragma unroll
        for (int ks = 0; ks < 4; ++ks) {
            acc00 = __builtin_amdgcn_mfma_f32_16x16x32_bf16(a0[ks], b0[ks], acc00, 0, 0, 0);
            acc01 = __builtin_amdgcn_mfma_f32_16x16x32_bf16(a0[ks], b1f[ks], acc01, 0, 0, 0);
            acc10 = __builtin_amdgcn_mfma_f32_16x16x32_bf16(a1[ks], b0[ks], acc10, 0, 0, 0);
            acc11 = __builtin_amdgcn_mfma_f32_16x16x32_bf16(a1[ks], b1f[ks], acc11, 0, 0, 0);
        }
        int mrow = ko * 4;
        int cb0 = wave * 32 + fr16;
#define EPI2_(FM, FN, ACC)                                                     \
    {                                                                          \
        int col = cb0 + FN * 16;                                               \
        float bv = b2l[col];                                                   \
        _Pragma("unroll") for (int r = 0; r < 4; ++r) {                        \
            int row = mrow + FM * 16 + r;                                      \
            int grow = node0 + row;                                            \
            float val = ACC[r] + bv + h[(size_t)grow * 128 + col];             \
            h[(size_t)grow * 128 + col] = val;                                 \
            hbl[row][col] = f2bf_bits(val);                                    \
        }                                                                      \
    }
        EPI2_(0, 0, acc00) EPI2_(0, 1, acc01) EPI2_(1, 0, acc10) EPI2_(1, 1, acc11)
#undef EPI2_
    }
    __syncthreads();

    // ---- GEMM1-next: uv_next = h' @ W1n ----
#pragma unroll
    for (int half = 0; half < 2; ++half) {
        int nt = wave + half * 4;
        const unsigned short* Bp = W1n + (size_t)(nt * 32 + fr16) * 128 + ko * 8;
        bf16x8 a0[4], a1[4], b0[4], b1f[4];
#pragma unroll
        for (int ks = 0; ks < 4; ++ks) {
            a0[ks] = *reinterpret_cast<const bf16x8*>(&hbl[fr16][ks * 32 + ko * 8]);
            a1[ks] = *reinterpret_cast<const bf16x8*>(&hbl[fr16 + 16][ks * 32 + ko * 8]);
            b0[ks] = *reinterpret_cast<const bf16x8*>(Bp + ks * 32);
            b1f[ks] = *reinterpret_cast<const bf16x8*>(Bp + 16 * 128 + ks * 32);
        }
        f32x4 acc00 = {0.f, 0.f, 0.f, 0.f}, acc01 = acc00, acc10 = acc00, acc11 = acc00;
#pragma unroll
        for (int ks = 0; ks < 4; ++ks) {
            acc00 = __builtin_amdgcn_mfma_f32_16x16x32_bf16(a0[ks], b0[ks], acc00, 0, 0, 0);
            acc01 = __builtin_amdgcn_mfma_f32_16x16x32_bf16(a0[ks], b1f[ks], acc01, 0, 0, 0);
            acc10 = __builtin_amdgcn_mfma_f32_16x16x32_bf16(a1[ks], b0[ks], acc10, 0, 0, 0);
            acc11 = __builtin_amdgcn_mfma_f32_16x16x32_bf16(a1[ks], b1f[ks], acc11, 0, 0, 0);
        }
        int mrow = ko * 4;
        int cb0 = nt * 32 + fr16;
#define EPI1_(FM, FN, ACC)                                                     \
    {                                                                          \
        int col = cb0 + FN * 16;                                               \
        _Pragma("unroll") for (int r = 0; r < 4; ++r) {                        \
            int row = mrow + FM * 16 + r;                                      \
            UVout[(size_t)(node0 + row) * 256 + col] = ACC[r];                 \
        }                                                                      \
    }
        EPI1_(0, 0, acc00) EPI1_(0, 1, acc01) EPI1_(1, 0, acc10) EPI1_(1, 1, acc11)
#undef EPI1_
    }
}

// ---------------- final head: per-edge weight, delta, output ----------------
__global__ __launch_bounds__(256) void k_final(const float* __restrict__ P,
                                               const int* __restrict__ idx,
                                               const float* __restrict__ nd,
                                               const float* __restrict__ nvec,
                                               const float* __restrict__ A1d,
                                               const float* __restrict__ a1v,
                                               const float* __restrict__ A2v,
                                               const float* __restrict__ a2v,
                                               const float* __restrict__ x,
                                               const float* __restrict__ cell,
                                               float* __restrict__ out) {
    __shared__ float plds[16][256];  // [e][g*16+fc]
    __shared__ float wlds[16][17];
    __shared__ float dclds[16][3];
    // XCD-friendly remap: the 64 blocks of one batch share blockIdx%8.
    int gb = blockIdx.x;
    int batch = (gb & 7) + 8 * (gb >> 9);
    int ib = (gb >> 3) & 63;
    int node0 = batch * N_ + ib * 16;
    int g = threadIdx.x >> 4, fc = threadIdx.x & 15;
    int node = node0 + g;
    int b = node >> 10;
    int f0 = fc * 8;
    float pa[8], ad[8], aa[8], a2r[8];
#pragma unroll
    for (int q = 0; q < 8; q += 4) {
        float4 t = *reinterpret_cast<const float4*>(&P[(size_t)node * 256 + f0 + q]);
        pa[q] = t.x; pa[q + 1] = t.y; pa[q + 2] = t.z; pa[q + 3] = t.w;
        float4 t2 = *reinterpret_cast<const float4*>(&A1d[f0 + q]);
        ad[q] = t2.x; ad[q + 1] = t2.y; ad[q + 2] = t2.z; ad[q + 3] = t2.w;
        float4 t3 = *reinterpret_cast<const float4*>(&a1v[f0 + q]);
        aa[q] = t3.x; aa[q + 1] = t3.y; aa[q + 2] = t3.z; aa[q + 3] = t3.w;
        float4 t4 = *reinterpret_cast<const float4*>(&A2v[f0 + q]);
        a2r[q] = t4.x; a2r[q + 1] = t4.y; a2r[q + 2] = t4.z; a2r[q + 3] = t4.w;
    }
    int ebase = node * K_;
    for (int e = 0; e < K_; ++e) {
        int j = idx[ebase + e];
        float dd = nd[ebase + e];
        const float* vp = &P[(size_t)(b * N_ + j) * 256 + 128 + f0];
        float part = 0.f;
#pragma unroll
        for (int q = 0; q < 8; q += 4) {
            float4 t = *reinterpret_cast<const float4*>(&vp[q]);
            float v4[4] = {t.x, t.y, t.z, t.w};
#pragma unroll
            for (int w = 0; w < 4; ++w) {
                float pre = pa[q + w] + v4[w] + fmaf(dd, ad[q + w], aa[q + w]);
                part = fmaf(silu_f(pre), a2r[q + w], part);
            }
        }
        plds[e][(g << 4) | fc] = part;
    }
    __syncthreads();
    {
        int g2 = threadIdx.x >> 4, e2 = threadIdx.x & 15;
        float w = a2v[0];
#pragma unroll
        for (int f2 = 0; f2 < 16; ++f2) w += plds[e2][(g2 << 4) | f2];
        wlds[g2][e2] = w;
    }
    __syncthreads();
    if (threadIdx.x < 48) {
        int gg = threadIdx.x & 15, c = threadIdx.x >> 4;
        int noded = node0 + gg;
        float dc = 0.f;
#pragma unroll
        for (int e = 0; e < K_; ++e)
            dc = fmaf(wlds[gg][e], nvec[(size_t)(noded * K_ + e) * 3 + c], dc);
        dclds[gg][c] = dc;
    }
    __syncthreads();
    if (threadIdx.x < 48) {
        int gg = threadIdx.x & 15, c = threadIdx.x >> 4;
        int noded = node0 + gg;
        int bb2 = noded >> 10;
        const float* cb = cell + bb2 * 9;
        float c00 = cb[0], c01 = cb[1], c02 = cb[2];
        float c10 = cb[3], c11 = cb[4], c12 = cb[5];
        float c20 = cb[6], c21 = cb[7], c22 = cb[8];
        float det = c00 * (c11 * c22 - c12 * c21) - c01 * (c10 * c22 - c12 * c20) +
                    c02 * (c10 * c21 - c11 * c20);
        float rdet = 1.0f / det;
        float i0c, i1c, i2c;  // column c of inv(cell)
        if (c == 0) {
            i0c = (c11 * c22 - c12 * c21) * rdet;
            i1c = -(c10 * c22 - c12 * c20) * rdet;
            i2c = (c10 * c21 - c11 * c20) * rdet;
        } else if (c == 1) {
            i0c = -(c01 * c22 - c02 * c21) * rdet;
            i1c = (c00 * c22 - c02 * c20) * rdet;
            i2c = -(c00 * c21 - c01 * c20) * rdet;
        } else {
            i0c = (c01 * c12 - c02 * c11) * rdet;
            i1c = -(c00 * c12 - c02 * c10) * rdet;
            i2c = (c00 * c11 - c01 * c10) * rdet;
        }
        float df = dclds[gg][0] * i0c + dclds[gg][1] * i1c + dclds[gg][2] * i2c;
        out[(size_t)noded * 3 + c] = x[(size_t)noded * 3 + c] + df;
    }
}

extern "C" void kernel_launch(void* const* d_in, const int* in_sizes, int n_in,
                              void* d_out, int out_size, void* d_ws, size_t ws_size,
                              hipStream_t stream) {
    (void)in_sizes; (void)n_in; (void)out_size; (void)ws_size;
    const float* cell = (const float*)d_in[0];
    const float* x    = (const float*)d_in[1];
    const int*   z    = (const int*)d_in[2];
    const float* emb  = (const float*)d_in[4];
    const float* W1   = (const float*)d_in[5];
    const float* b1   = (const float*)d_in[6];
    const float* W2   = (const float*)d_in[7];
    const float* b2   = (const float*)d_in[8];
    const float* A1   = (const float*)d_in[9];
    const float* a1   = (const float*)d_in[10];
    const float* A2   = (const float*)d_in[11];
    const float* a2   = (const float*)d_in[12];
    float* out = (float*)d_out;

    char* ws = (char*)d_ws;
    size_t off = 0;
    auto alloc = [&](size_t bytes) {
        void* p = ws + off;
        off = (off + bytes + 255) & ~(size_t)255;
        return p;
    };
    int* idx    = (int*)alloc((size_t)B_ * N_ * K_ * 4);
    float* nd   = (float*)alloc((size_t)B_ * N_ * K_ * 4);
    float* nvec = (float*)alloc((size_t)B_ * N_ * K_ * 3 * 4);
    float* h0   = (float*)alloc((size_t)B_ * N_ * F_ * 4);
    float* uv0  = (float*)alloc((size_t)B_ * N_ * 256 * 4);
    float* uv1  = (float*)alloc((size_t)B_ * N_ * 256 * 4);
    unsigned short* hbf = (unsigned short*)alloc((size_t)B_ * N_ * F_ * 2);
    unsigned short* Wt1 = (unsigned short*)alloc((size_t)L_ * 256 * 128 * 2);
    unsigned short* Wt2 = (unsigned short*)alloc((size_t)L_ * 128 * 128 * 2);
    unsigned short* At1 = (unsigned short*)alloc((size_t)256 * 128 * 2);

    int conv_total = L_ * 256 * 128 + L_ * 128 * 128 + 256 * 128;
    k_wconv<<<(conv_total + 255) / 256, 256, 0, stream>>>(W1, W2, A1, Wt1, Wt2, At1);
    k_embed<<<2048, 256, 0, stream>>>(z, emb, h0, hbf);
    k_knn<<<4096, 256, 0, stream>>>(x, cell, idx, nvec, nd);

    // G1 of layer 0: uv0 = h0 @ W1ab(0)
    k_wgemm<3><<<1024, 256, 0, stream>>>(hbf, Wt1, uv0, 256);

    for (int l = 0; l < L_; ++l) {
        const float* uin = (l & 1) ? uv1 : uv0;
        float* uout = (l & 1) ? uv0 : uv1;
        const unsigned short* W1next = (l < 3) ? (Wt1 + (size_t)(l + 1) * 256 * 128) : At1;
        k_layer<<<512, 256, 0, stream>>>(uin, idx, nd,
                                         W1 + (size_t)l * DIN_ * F_ + 256 * F_, b1 + l * F_,
                                         Wt2 + (size_t)l * 128 * 128, b2 + l * F_, h0,
                                         W1next, uout);
    }
    k_final<<<1024, 256, 0, stream>>>(uv0, idx, nd, nvec, A1 + 256 * F_, a1, A2, a2, x, cell,
                                      out);
}